// Round 11
// baseline (50.661 us; speedup 1.0000x reference)
//
#include <hip/hip_runtime.h>

constexpr int B = 64, N = 8732, C = 21, M = 16;
constexpr int TROW = 1 + 6 * M;       // 97
constexpr int NBIN = 4096;            // windowed 16-bit-float bins
constexpr unsigned BASE16 = 15103u;   // key16 window start (logp0 ~ -2048)
constexpr int NSLAB = 8;              // slab replicas
constexpr int APB = 512;              // anchors per block (4 thr/anchor)
constexpr int CHUNKS = (N + APB - 1) / APB;  // 18
constexpr float FSCALE = 262144.0f;   // 2^18 fixed-point for CE sums
constexpr unsigned long long CNT1 = 1ull << 44;
constexpr unsigned long long FIXMASK = (1ull << 44) - 1;

__device__ __forceinline__ unsigned f2key(float f) {
  unsigned u = __float_as_uint(f);
  return (u & 0x80000000u) ? ~u : (u | 0x80000000u);
}
__device__ __forceinline__ float key2f(unsigned k) {
  unsigned u = (k & 0x80000000u) ? (k ^ 0x80000000u) : ~k;
  return __uint_as_float(u);
}

// ---- zero the slabs (8 * 4096 u64 = 256 KB) ----
__global__ __launch_bounds__(256) void k_zero(unsigned long long* __restrict__ z) {
  int idx = blockIdx.x * 256 + threadIdx.x;   // 128 blocks * 256 = 32768
  z[idx] = 0ull;
}

// ---- logp: 4 thr/anchor direct-global; windowed LDS hist; fused targets ----
__global__ __launch_bounds__(256) void k_logp(
    const float* __restrict__ conf, const float* __restrict__ bbox,
    const float* __restrict__ target, const float* __restrict__ pred,
    unsigned long long* __restrict__ slab1, float4* __restrict__ batchCtl) {
  __shared__ unsigned long long shist[NBIN];   // 32 KB
  __shared__ int sk[M];
  int b = blockIdx.y, bx = blockIdx.x, tid = threadIdx.x;

  for (int i = tid; i < NBIN; i += 256) shist[i] = 0ull;
  const float* tr = target + (size_t)b * TROW;
  if (tid < M) {
    int num = (int)tr[0];
    sk[tid] = (tid < num) ? (int)tr[1 + 6 * tid + 5] : -1;
  }
  __syncthreads();

  int lj = tid & 3;        // lane within 4-thread group
  int grp = tid >> 2;      // anchor slot (0..63)

  #pragma unroll
  for (int it = 0; it < APB / 64; ++it) {
    int n = bx * APB + it * 64 + grp;
    if (n < N) {
      const float* row = conf + ((size_t)b * N + n) * C;
      float v0 = row[lj];
      float v1 = row[lj + 4];
      float v2 = row[lj + 8];
      float v3 = row[lj + 12];
      float v4 = row[lj + 16];
      float v5 = (lj == 1) ? row[20] : -3.4e38f;
      float mx = fmaxf(fmaxf(fmaxf(v0, v1), fmaxf(v2, v3)), fmaxf(v4, v5));
      mx = fmaxf(mx, __shfl_xor(mx, 1, 64));
      mx = fmaxf(mx, __shfl_xor(mx, 2, 64));
      float s = __expf(v0 - mx) + __expf(v1 - mx) + __expf(v2 - mx) +
                __expf(v3 - mx) + __expf(v4 - mx);
      if (lj == 1) s += __expf(v5 - mx);
      s += __shfl_xor(s, 1, 64);
      s += __shfl_xor(s, 2, 64);
      if (lj == 0) {
        float logp0 = v0 - mx - __logf(s);
        bool asg = false;
        for (int j = 0; j < M; j++) asg |= (sk[j] == n);
        if (!asg) {
          int idx = (int)(f2key(logp0) >> 16) - (int)BASE16;
          idx = min(max(idx, 0), NBIN - 1);
          atomicAdd(&shist[idx],
                    CNT1 | (unsigned long long)((-logp0) * FSCALE + 0.5f));
        }
      }
    }
  }
  __syncthreads();

  unsigned long long* sg =
      slab1 + (size_t)((b * CHUNKS + bx) & (NSLAB - 1)) * NBIN;
  for (int i = tid; i < NBIN; i += 256) {
    unsigned long long v = shist[i];
    if (v) atomicAdd(&sg[i], v);
  }

  if (bx == 0) {
    float myValid = 0.f, myPos = 0.f, myCE = 0.f, mySL = 0.f;
    if (tid < M && sk[tid] >= 0) {
      const float* e = tr + 1 + 6 * tid;
      int cls = (int)e[0];
      float tx1 = e[1], ty1 = e[2], tx2 = e[3], ty2 = e[4];
      int k = sk[tid];
      float p0 = pred[k * 4 + 0], p1 = pred[k * 4 + 1];
      float p2 = pred[k * 4 + 2], p3 = pred[k * 4 + 3];
      float pw = p2 - p0, ph = p3 - p1;
      float pcx = (p0 + p2) * 0.5f, pcy = (p1 + p3) * 0.5f;
      float tw = tx2 - tx1, th = ty2 - ty1;
      float tcx = (tx1 + tx2) * 0.5f, tcy = (ty1 + ty2) * 0.5f;
      float ebv[4];
      ebv[0] = (tcx - pcx) / pw;
      ebv[1] = (tcy - pcy) / ph;
      ebv[2] = __logf(tw / pw);
      ebv[3] = __logf(th / ph);
      const float* bo = bbox + ((size_t)b * N + k) * 4;
      float sl = 0.f;
      for (int j = 0; j < 4; j++) {
        float d = bo[j] - ebv[j];
        float ad = fabsf(d);
        sl += (ad < 1.f) ? 0.5f * d * d : ad - 0.5f;
      }
      myValid = 1.f; mySL = sl;
      if (cls > 0) {
        const float* x = conf + ((size_t)b * N + k) * C;
        float mx = x[0];
        for (int c = 1; c < C; c++) mx = fmaxf(mx, x[c]);
        float s = 0.f;
        for (int c = 0; c < C; c++) s += __expf(x[c] - mx);
        float lp = x[cls] - mx - __logf(s);
        myPos = 1.f; myCE = -lp;
      }
    }
    if (tid < 64) {
      for (int off = 32; off; off >>= 1) {
        myValid += __shfl_down(myValid, off, 64);
        myPos   += __shfl_down(myPos, off, 64);
        myCE    += __shfl_down(myCE, off, 64);
        mySL    += __shfl_down(mySL, off, 64);
      }
      if (tid == 0) batchCtl[b] = make_float4(myPos, myValid, myCE, mySL);
    }
  }
}

// ---- fin: reduce slabs + scan + interpolate + outputs (1 block, 1024 thr) ----
__global__ __launch_bounds__(1024) void k_fin(
    const unsigned long long* __restrict__ slab1,
    const float4* __restrict__ batchCtl, float* __restrict__ out) {
  __shared__ unsigned long long sm[NBIN];      // 32 KB
  __shared__ unsigned long long sscan[1024];   // 8 KB
  __shared__ unsigned srank;
  __shared__ float sp, sva, sce, ssl;
  __shared__ double sNeg;
  int tid = threadIdx.x;

  if (tid < 64) {
    float4 v = batchCtl[tid];
    float p = v.x, va = v.y, ce = v.z, sl = v.w;
    for (int off = 32; off; off >>= 1) {
      p  += __shfl_down(p, off, 64);
      va += __shfl_down(va, off, 64);
      ce += __shfl_down(ce, off, 64);
      sl += __shfl_down(sl, off, 64);
    }
    if (tid == 0) {
      sp = p; sva = va; sce = ce; ssl = sl;
      srank = 3u * (unsigned)(p + 0.5f);
      sNeg = 0.0;
    }
  }

  // coalesced slab reduce
  for (int k = 0; k < NBIN / 1024; k++) {
    int bin = tid + k * 1024;
    unsigned long long v = 0ull;
    for (int s = 0; s < NSLAB; s++) v += slab1[(size_t)s * NBIN + bin];
    sm[bin] = v;
  }
  __syncthreads();

  unsigned long long h4[4];
  unsigned long long part = 0ull;
  for (int j = 0; j < 4; j++) { h4[j] = sm[tid * 4 + j]; part += h4[j]; }
  sscan[tid] = part;
  __syncthreads();
  for (int off = 1; off < 1024; off <<= 1) {
    unsigned long long add = (tid >= off) ? sscan[tid - off] : 0ull;
    __syncthreads();
    sscan[tid] += add;
    __syncthreads();
  }

  unsigned rank = srank;
  if (rank) {
    unsigned long long cum = sscan[tid] - part;
    for (int j = 0; j < 4; j++) {
      unsigned long long h = h4[j];
      unsigned c0 = (unsigned)(cum >> 44);
      unsigned c1 = (unsigned)((cum + h) >> 44);
      if (c0 < rank && c1 >= rank) {
        unsigned t = (unsigned)(tid * 4 + j);
        unsigned r = rank - c0;
        unsigned long long fixBelow = cum & FIXMASK;
        float ceEdge = -key2f((BASE16 + t) << 16);
        sNeg = (double)fixBelow / 262144.0 + (double)r * (double)ceEdge;
      }
      cum += h;
    }
  }
  __syncthreads();
  if (tid == 0) {
    out[0] = (sce + (float)sNeg) / fmaxf(4.0f * sp, 1.0f);
    out[1] = ssl / fmaxf(4.0f * sva, 1.0f);
  }
}

extern "C" void kernel_launch(void* const* d_in, const int* in_sizes, int n_in,
                              void* d_out, int out_size, void* d_ws, size_t ws_size,
                              hipStream_t stream) {
  const float* conf = (const float*)d_in[0];
  const float* bbox = (const float*)d_in[1];
  const float* target = (const float*)d_in[2];
  const float* pred = (const float*)d_in[3];
  float* out = (float*)d_out;

  char* ws = (char*)d_ws;
  unsigned long long* slab1 = (unsigned long long*)ws;
  size_t off = (size_t)NSLAB * NBIN * 8;                // 256 KB
  float4* batchCtl = (float4*)(ws + off); off += 64 * 16;

  k_zero<<<128, 256, 0, stream>>>(slab1);
  k_logp<<<dim3(CHUNKS, B), 256, 0, stream>>>(conf, bbox, target, pred,
                                              slab1, batchCtl);
  k_fin<<<1, 1024, 0, stream>>>(slab1, batchCtl, out);
}

// Round 12
// 42.362 us; speedup vs baseline: 1.1959x; 1.1959x over previous
//
#include <hip/hip_runtime.h>

constexpr int B = 64, N = 8732, C = 21, M = 16;
constexpr int TROW = 1 + 6 * M;       // 97
constexpr int NBIN = 2048;            // windowed bins, 2 float16-key steps wide
constexpr unsigned BASE16 = 15103u;   // key16 window start
constexpr int NSLAB = 8;              // slab replicas
constexpr int APB = 256;              // anchors per block (4 thr/anchor, 4 iters)
constexpr int CHUNKS = (N + APB - 1) / APB;  // 35
constexpr float FSCALE = 262144.0f;   // 2^18 fixed-point for CE sums
constexpr unsigned long long CNT1 = 1ull << 44;
constexpr unsigned long long FIXMASK = (1ull << 44) - 1;

__device__ __forceinline__ unsigned f2key(float f) {
  unsigned u = __float_as_uint(f);
  return (u & 0x80000000u) ? ~u : (u | 0x80000000u);
}
__device__ __forceinline__ float key2f(unsigned k) {
  unsigned u = (k & 0x80000000u) ? (k ^ 0x80000000u) : ~k;
  return __uint_as_float(u);
}

// ---- zero the slabs (8 * 2048 u64 = 128 KB) ----
__global__ __launch_bounds__(256) void k_zero(unsigned long long* __restrict__ z) {
  int idx = blockIdx.x * 256 + threadIdx.x;   // 64 blocks * 256 = 16384
  z[idx] = 0ull;
}

// ---- logp: 4 thr/anchor, no max-sub, 16KB windowed hist; fused targets ----
__global__ __launch_bounds__(256) void k_logp(
    const float* __restrict__ conf, const float* __restrict__ bbox,
    const float* __restrict__ target, const float* __restrict__ pred,
    unsigned long long* __restrict__ slab1, float4* __restrict__ batchCtl) {
  __shared__ unsigned long long shist[NBIN];   // 16 KB
  __shared__ int sk[M];
  int b = blockIdx.y, bx = blockIdx.x, tid = threadIdx.x;

  for (int i = tid; i < NBIN; i += 256) shist[i] = 0ull;
  const float* tr = target + (size_t)b * TROW;
  if (tid < M) {
    int num = (int)tr[0];
    sk[tid] = (tid < num) ? (int)tr[1 + 6 * tid + 5] : -1;
  }
  __syncthreads();

  int lj = tid & 3;        // lane within 4-thread group
  int grp = tid >> 2;      // anchor slot (0..63)

  #pragma unroll
  for (int it = 0; it < APB / 64; ++it) {
    int n = bx * APB + it * 64 + grp;
    if (n < N) {
      const float* row = conf + ((size_t)b * N + n) * C;
      float v0 = row[lj];
      float v1 = row[lj + 4];
      float v2 = row[lj + 8];
      float v3 = row[lj + 12];
      float v4 = row[lj + 16];
      float s = __expf(v0) + __expf(v1) + __expf(v2) + __expf(v3) + __expf(v4);
      if (lj == 1) s += __expf(row[20]);
      s += __shfl_xor(s, 1, 64);
      s += __shfl_xor(s, 2, 64);
      if (lj == 0) {
        float logp0 = v0 - __logf(s);
        bool asg = false;
        for (int j = 0; j < M; j++) asg |= (sk[j] == n);
        if (!asg) {
          int idx = ((int)(f2key(logp0) >> 16) - (int)BASE16) >> 1;
          idx = min(max(idx, 0), NBIN - 1);
          atomicAdd(&shist[idx],
                    CNT1 | (unsigned long long)((-logp0) * FSCALE + 0.5f));
        }
      }
    }
  }
  __syncthreads();

  unsigned long long* sg =
      slab1 + (size_t)((b * CHUNKS + bx) & (NSLAB - 1)) * NBIN;
  for (int i = tid; i < NBIN; i += 256) {
    unsigned long long v = shist[i];
    if (v) atomicAdd(&sg[i], v);
  }

  if (bx == 0) {
    float myValid = 0.f, myPos = 0.f, myCE = 0.f, mySL = 0.f;
    if (tid < M && sk[tid] >= 0) {
      const float* e = tr + 1 + 6 * tid;
      int cls = (int)e[0];
      float tx1 = e[1], ty1 = e[2], tx2 = e[3], ty2 = e[4];
      int k = sk[tid];
      float p0 = pred[k * 4 + 0], p1 = pred[k * 4 + 1];
      float p2 = pred[k * 4 + 2], p3 = pred[k * 4 + 3];
      float pw = p2 - p0, ph = p3 - p1;
      float pcx = (p0 + p2) * 0.5f, pcy = (p1 + p3) * 0.5f;
      float tw = tx2 - tx1, th = ty2 - ty1;
      float tcx = (tx1 + tx2) * 0.5f, tcy = (ty1 + ty2) * 0.5f;
      float ebv[4];
      ebv[0] = (tcx - pcx) / pw;
      ebv[1] = (tcy - pcy) / ph;
      ebv[2] = __logf(tw / pw);
      ebv[3] = __logf(th / ph);
      const float* bo = bbox + ((size_t)b * N + k) * 4;
      float sl = 0.f;
      for (int j = 0; j < 4; j++) {
        float d = bo[j] - ebv[j];
        float ad = fabsf(d);
        sl += (ad < 1.f) ? 0.5f * d * d : ad - 0.5f;
      }
      myValid = 1.f; mySL = sl;
      if (cls > 0) {
        const float* x = conf + ((size_t)b * N + k) * C;
        float s = 0.f;
        for (int c = 0; c < C; c++) s += __expf(x[c]);
        float lp = x[cls] - __logf(s);
        myPos = 1.f; myCE = -lp;
      }
    }
    if (tid < 64) {
      for (int off = 32; off; off >>= 1) {
        myValid += __shfl_down(myValid, off, 64);
        myPos   += __shfl_down(myPos, off, 64);
        myCE    += __shfl_down(myCE, off, 64);
        mySL    += __shfl_down(mySL, off, 64);
      }
      if (tid == 0) batchCtl[b] = make_float4(myPos, myValid, myCE, mySL);
    }
  }
}

// ---- fin: reduce slabs + scan + interpolate + outputs (1 block, 1024 thr) ----
__global__ __launch_bounds__(1024) void k_fin(
    const unsigned long long* __restrict__ slab1,
    const float4* __restrict__ batchCtl, float* __restrict__ out) {
  __shared__ unsigned long long sm[NBIN];      // 16 KB
  __shared__ unsigned long long sscan[1024];   // 8 KB
  __shared__ unsigned srank;
  __shared__ float sp, sva, sce, ssl;
  __shared__ double sNeg;
  int tid = threadIdx.x;

  if (tid < 64) {
    float4 v = batchCtl[tid];
    float p = v.x, va = v.y, ce = v.z, sl = v.w;
    for (int off = 32; off; off >>= 1) {
      p  += __shfl_down(p, off, 64);
      va += __shfl_down(va, off, 64);
      ce += __shfl_down(ce, off, 64);
      sl += __shfl_down(sl, off, 64);
    }
    if (tid == 0) {
      sp = p; sva = va; sce = ce; ssl = sl;
      srank = 3u * (unsigned)(p + 0.5f);
      sNeg = 0.0;
    }
  }

  // coalesced slab reduce (2 bins per thread)
  for (int k = 0; k < NBIN / 1024; k++) {
    int bin = tid + k * 1024;
    unsigned long long v = 0ull;
    for (int s = 0; s < NSLAB; s++) v += slab1[(size_t)s * NBIN + bin];
    sm[bin] = v;
  }
  __syncthreads();

  unsigned long long h2[2];
  unsigned long long part = 0ull;
  for (int j = 0; j < 2; j++) { h2[j] = sm[tid * 2 + j]; part += h2[j]; }
  sscan[tid] = part;
  __syncthreads();
  for (int off = 1; off < 1024; off <<= 1) {
    unsigned long long add = (tid >= off) ? sscan[tid - off] : 0ull;
    __syncthreads();
    sscan[tid] += add;
    __syncthreads();
  }

  unsigned rank = srank;
  if (rank) {
    unsigned long long cum = sscan[tid] - part;
    for (int j = 0; j < 2; j++) {
      unsigned long long h = h2[j];
      unsigned c0 = (unsigned)(cum >> 44);
      unsigned c1 = (unsigned)((cum + h) >> 44);
      if (c0 < rank && c1 >= rank) {
        unsigned t = (unsigned)(tid * 2 + j);
        unsigned r = rank - c0;
        unsigned long long fixBelow = cum & FIXMASK;
        float ceEdge = -key2f((BASE16 + 2u * t) << 16);
        sNeg = (double)fixBelow / 262144.0 + (double)r * (double)ceEdge;
      }
      cum += h;
    }
  }
  __syncthreads();
  if (tid == 0) {
    out[0] = (sce + (float)sNeg) / fmaxf(4.0f * sp, 1.0f);
    out[1] = ssl / fmaxf(4.0f * sva, 1.0f);
  }
}

extern "C" void kernel_launch(void* const* d_in, const int* in_sizes, int n_in,
                              void* d_out, int out_size, void* d_ws, size_t ws_size,
                              hipStream_t stream) {
  const float* conf = (const float*)d_in[0];
  const float* bbox = (const float*)d_in[1];
  const float* target = (const float*)d_in[2];
  const float* pred = (const float*)d_in[3];
  float* out = (float*)d_out;

  char* ws = (char*)d_ws;
  unsigned long long* slab1 = (unsigned long long*)ws;
  size_t off = (size_t)NSLAB * NBIN * 8;                // 128 KB
  float4* batchCtl = (float4*)(ws + off); off += 64 * 16;

  k_zero<<<64, 256, 0, stream>>>(slab1);
  k_logp<<<dim3(CHUNKS, B), 256, 0, stream>>>(conf, bbox, target, pred,
                                              slab1, batchCtl);
  k_fin<<<1, 1024, 0, stream>>>(slab1, batchCtl, out);
}